// Round 1
// baseline (434.256 us; speedup 1.0000x reference)
//
#include <hip/hip_runtime.h>

// PNN fused kernel for MI355X (gfx950).
// B=16384 rows. Per block: 64 rows, 8 waves; wave w handles f = w, w+8, ...
// Each lane owns one row; acc[64] = (first[0..31], s[0..31]) partials in VGPRs.
// w_first/w_inner accesses are wave-uniform (f uniform per wave via
// readfirstlane; d,e are unrolled constants) -> scalar loads, inner loop is
// pure v_fmac. Partials merged across waves via ds-atomic fp32 adds into a
// [d][row] LDS tile (lane-consecutive -> conflict-free), then wave 0 runs the
// tiny MLP per row and stores out[b].

namespace {

constexpr int Bn = 16384;
constexpr int Fn = 39;
constexpr int Vn = 100000;
constexpr int En = 16;
constexpr int WAVES = 8;
constexpr int THREADS = WAVES * 64;   // 512
constexpr int ROWS = 64;              // rows per block

__global__ __launch_bounds__(THREADS, 2) void pnn_fused(
    const int* __restrict__ Xi,
    const float* __restrict__ Xv,
    const float* __restrict__ T,
    const float* __restrict__ w_first,
    const float* __restrict__ w_inner,
    const float* __restrict__ lin1_W,
    const float* __restrict__ lin1_b,
    const float* __restrict__ lin2_W,
    const float* __restrict__ lin2_b,
    const float* __restrict__ last_W,
    const float* __restrict__ last_b,
    float* __restrict__ out)
{
    __shared__ float x_lds[64 * ROWS];   // [d][row], 16 KB

    const int lane = threadIdx.x & 63;
    const int wv = __builtin_amdgcn_readfirstlane(threadIdx.x >> 6);
    const int row = blockIdx.x * ROWS + lane;

    // zero the reduction tile
    for (int i = threadIdx.x; i < 64 * ROWS; i += THREADS) x_lds[i] = 0.0f;
    __syncthreads();

    float acc[64];
#pragma unroll
    for (int d = 0; d < 64; ++d) acc[d] = 0.0f;

    // software-pipelined gather: fetch f's row while computing previous f
    int f = wv;
    float4 g0 = {0, 0, 0, 0}, g1 = {0, 0, 0, 0}, g2 = {0, 0, 0, 0}, g3 = {0, 0, 0, 0};
    float xv = 0.0f;
    if (f < Fn) {
        const int idx = Xi[row * Fn + f];
        xv = Xv[row * Fn + f];
        const float4* src = reinterpret_cast<const float4*>(
            T + (size_t)f * Vn * En + (size_t)idx * En);
        g0 = src[0]; g1 = src[1]; g2 = src[2]; g3 = src[3];
    }

    while (f < Fn) {
        const int fn = f + WAVES;
        float4 h0 = {0, 0, 0, 0}, h1 = {0, 0, 0, 0}, h2 = {0, 0, 0, 0}, h3 = {0, 0, 0, 0};
        float xvn = 0.0f;
        if (fn < Fn) {
            const int idxn = Xi[row * Fn + fn];
            xvn = Xv[row * Fn + fn];
            const float4* src = reinterpret_cast<const float4*>(
                T + (size_t)fn * Vn * En + (size_t)idxn * En);
            h0 = src[0]; h1 = src[1]; h2 = src[2]; h3 = src[3];
        }

        float ev[16] = {g0.x, g0.y, g0.z, g0.w, g1.x, g1.y, g1.z, g1.w,
                        g2.x, g2.y, g2.z, g2.w, g3.x, g3.y, g3.z, g3.w};
#pragma unroll
        for (int e = 0; e < 16; ++e) ev[e] *= xv;

        const float* wf = w_first + f * En;   // w_first[d][f][e] = d*F*E + f*E + e
        const float* wi = w_inner + f * En;
#pragma unroll
        for (int d = 0; d < 32; ++d) {
            const float* wr = wf + d * (Fn * En);
            float a = acc[d];
#pragma unroll
            for (int e = 0; e < 16; ++e) a = fmaf(ev[e], wr[e], a);
            acc[d] = a;
        }
#pragma unroll
        for (int d = 0; d < 32; ++d) {
            const float* wr = wi + d * (Fn * En);
            float a = acc[32 + d];
#pragma unroll
            for (int e = 0; e < 16; ++e) a = fmaf(ev[e], wr[e], a);
            acc[32 + d] = a;
        }

        f = fn;
        g0 = h0; g1 = h1; g2 = h2; g3 = h3;
        xv = xvn;
    }

    // cross-wave reduction: [d][row] layout, lane-consecutive -> conflict-free
#pragma unroll
    for (int d = 0; d < 64; ++d) atomicAdd(&x_lds[d * ROWS + lane], acc[d]);
    __syncthreads();

    // fused MLP: one lane per row (wave 0 only); all weights wave-uniform
    if (threadIdx.x < 64) {
        const int r = lane;
        float xin[32];
#pragma unroll
        for (int j = 0; j < 32; ++j) {
            const float fi = x_lds[j * ROWS + r];
            const float s = x_lds[(32 + j) * ROWS + r];
            xin[j] = fi + s * s;
        }
        float y1[32];
#pragma unroll
        for (int i = 0; i < 32; ++i) {
            float t = lin1_b[i];
#pragma unroll
            for (int j = 0; j < 32; ++j) t = fmaf(lin1_W[i * 32 + j], xin[j], t);
            y1[i] = fmaxf(t, 0.0f);
        }
        float y2[32];
#pragma unroll
        for (int i = 0; i < 32; ++i) {
            float t = lin2_b[i];
#pragma unroll
            for (int j = 0; j < 32; ++j) t = fmaf(lin2_W[i * 32 + j], y1[j], t);
            y2[i] = fmaxf(t, 0.0f);
        }
        float res = last_b[0];
#pragma unroll
        for (int j = 0; j < 32; ++j) res = fmaf(last_W[j], y2[j], res);
        out[blockIdx.x * ROWS + r] = res;
    }
}

} // namespace

extern "C" void kernel_launch(void* const* d_in, const int* in_sizes, int n_in,
                              void* d_out, int out_size, void* d_ws, size_t ws_size,
                              hipStream_t stream) {
    const int*   Xi      = (const int*)d_in[0];
    const float* Xv      = (const float*)d_in[1];
    const float* T       = (const float*)d_in[2];
    const float* w_first = (const float*)d_in[3];
    const float* w_inner = (const float*)d_in[4];
    const float* lin1_W  = (const float*)d_in[5];
    const float* lin1_b  = (const float*)d_in[6];
    const float* lin2_W  = (const float*)d_in[7];
    const float* lin2_b  = (const float*)d_in[8];
    const float* last_W  = (const float*)d_in[9];
    const float* last_b  = (const float*)d_in[10];
    float* out = (float*)d_out;

    dim3 grid(Bn / ROWS);    // 256 blocks -> 1 block/CU, 8 waves each
    dim3 block(THREADS);     // 512
    hipLaunchKernelGGL(pnn_fused, grid, block, 0, stream,
                       Xi, Xv, T, w_first, w_inner,
                       lin1_W, lin1_b, lin2_W, lin2_b, last_W, last_b, out);
}